// Round 3
// baseline (2449.004 us; speedup 1.0000x reference)
//
#include <hip/hip_runtime.h>

// FunctionCorrelationTranspose:
// out[b,c,h,w] = (1/C) * sum_{P=0..8,O=0..8} input[b, P*9+O, h, w] * second[b, c, h+P-4, w+O-4]
// B=8, C=256, H=W=128, zero padding outside image.
//
// R3: double-buffered LDS staging overlapped with compute.
//  - 512-thread block, 2 x 32-channel LDS buffers (148 KB) -> 1 block/CU, 8 waves/CU
//  - stage(k+1) issued AFTER all weight loads of chunk k (youngest in vmcnt FIFO,
//    pinned by sched_barrier) so weight waits never drain it; the end-of-chunk
//    __syncthreads' vmcnt(0) lands after a full compute phase of cover.
//  - NPIX=4 (halves ping-pong weight regs), NC=4 (weight re-reads stay 8x)
//  - plain float4 stores (R2's nontemporal stores caused RMW: WRITE 131->199 MB)

#define MD 4

constexpr int Bc = 8, Cc = 256, Hc = 128, Wc = 128;
constexpr int HW = Hc * Wc;
constexpr int TH = 16, TW = 16;          // spatial tile per block
constexpr int NSLOT = 8;                 // channel slots (threads along C)
constexpr int NC = 4;                    // channels per thread per chunk
constexpr int CHUNK = NSLOT * NC;        // 32 channels per LDS buffer
constexpr int NCHUNK = Cc / CHUNK;       // 8
constexpr int SROWS = TH + 2 * MD;       // 24
constexpr int SCOLS = TW + 2 * MD;       // 24
constexpr int CH_STRIDE = SROWS * SCOLS + 4; // 580 floats; slot bank-starts {0,4,..,28}
constexpr int SLOTS_PER_CH = CH_STRIDE / 4;  // 145 16B-slots per channel (144 data + 1 pad)
constexpr int BUF_SLOTS = CHUNK * SLOTS_PER_CH;  // 4640 16B-slots per buffer
constexpr int BUF_FLOATS = CHUNK * CH_STRIDE;    // 18560 floats (74,240 B) per buffer
constexpr int NPIX = 4;                  // pixels per thread (contiguous in w)
constexpr int NT = 512;                  // threads per block

// load the 9 taps of weight-row PP for this thread's 4 pixels into dst[9]
#define LOADW(dst, PP)                                                  \
    {                                                                   \
        _Pragma("unroll")                                               \
        for (int o = 0; o < 9; ++o) {                                   \
            const float* wp = wbase + (size_t)((PP) * 9 + o) * HW;      \
            dst[o] = *reinterpret_cast<const float4*>(wp);              \
        }                                                               \
    }

// accumulate one weight-row PP using weights in wcur[9]
#define COMPUTE(wcur, PP)                                                        \
    {                                                                            \
        _Pragma("unroll")                                                        \
        for (int j = 0; j < NC; ++j) {                                           \
            const int cl = j * NSLOT + slot;                                     \
            const float* srow = bufS + cl * CH_STRIDE + (r + (PP)) * SCOLS + seg * NPIX; \
            float s[12];                                                         \
            _Pragma("unroll")                                                    \
            for (int t = 0; t < 3; ++t) {                                        \
                float4 v = *reinterpret_cast<const float4*>(srow + 4 * t);       \
                s[4*t] = v.x; s[4*t+1] = v.y; s[4*t+2] = v.z; s[4*t+3] = v.w;    \
            }                                                                    \
            _Pragma("unroll")                                                    \
            for (int o = 0; o < 9; ++o) {                                        \
                acc[j][0] = fmaf(wcur[o].x, s[o + 0], acc[j][0]);                \
                acc[j][1] = fmaf(wcur[o].y, s[o + 1], acc[j][1]);                \
                acc[j][2] = fmaf(wcur[o].z, s[o + 2], acc[j][2]);                \
                acc[j][3] = fmaf(wcur[o].w, s[o + 3], acc[j][3]);                \
            }                                                                    \
        }                                                                        \
    }

// async-stage chunk KK's 32-channel halo tile into LDS buffer BSEL.
// LDS image per buffer is linear in 16B slots: slot m = ch*145 + k; k<144 data,
// k==144 pad (never written -> stays zero). global_load_lds writes wave-uniform
// base + lane*16, matching m. OOB slots are exec-masked off (zeros persist; the
// OOB pattern depends only on (row,x,tile) so it is identical every restage).
#define STAGE(KK, BSEL)                                                          \
    {                                                                            \
        const int c0_ = (KK) * CHUNK;                                            \
        float* base_ = sS + (BSEL) * BUF_FLOATS;                                 \
        _Pragma("unroll")                                                        \
        for (int it = 0; it < 10; ++it) {                                        \
            const int m_ = it * NT + tid;                                        \
            if (m_ < BUF_SLOTS) {                                                \
                const int ch_   = m_ / SLOTS_PER_CH;                             \
                const int kk_   = m_ - ch_ * SLOTS_PER_CH;                       \
                const int row_  = kk_ / 6;                                       \
                const int x_    = kk_ - row_ * 6;                                \
                const int grow_ = th0 - MD + row_;                               \
                const int gcol_ = tw0 - MD + 4 * x_;                             \
                float* ldsb_ = base_ + (size_t)(it * NT + wid * 64) * 4;         \
                if (kk_ < 144 && grow_ >= 0 && grow_ < Hc &&                     \
                    gcol_ >= 0 && gcol_ <= Wc - 4) {                             \
                    const float* gp_ = second +                                  \
                        (((size_t)(b * Cc + c0_ + ch_)) * Hc + grow_) * Wc + gcol_; \
                    __builtin_amdgcn_global_load_lds(                            \
                        (const __attribute__((address_space(1))) void*)gp_,      \
                        (__attribute__((address_space(3))) void*)ldsb_,          \
                        16, 0, 0);                                               \
                }                                                                \
            }                                                                    \
        }                                                                        \
    }

__global__ __launch_bounds__(NT, 2)
void fct_kernel(const float* __restrict__ inp,    // (B, 81, H, W)
                const float* __restrict__ second, // (B, C, H, W)
                float* __restrict__ out)          // (B, C, H, W)
{
    __shared__ __attribute__((aligned(16))) float sS[2 * BUF_FLOATS]; // 148,480 B

    const int tid   = threadIdx.x;
    const int slot  = tid & (NSLOT - 1);   // 0..7  channel slot
    const int group = tid >> 3;            // 0..63 pixel group
    const int seg   = group & 3;           // 0..3  4-px segment in row
    const int r     = group >> 2;          // 0..15 tile row
    const int wid   = tid >> 6;            // wave id 0..7

    const int bx   = blockIdx.x;           // 0..511
    const int b    = bx >> 6;
    const int tile = bx & 63;
    const int th0  = (tile >> 3) * TH;
    const int tw0  = (tile & 7) * TW;

    const int h   = th0 + r;
    const int wc0 = tw0 + seg * NPIX;

    // zero both LDS buffers once: OOB halo cells must read as 0 forever
    {
        float4 z = make_float4(0.f, 0.f, 0.f, 0.f);
        float4* s4 = reinterpret_cast<float4*>(sS);
        #pragma unroll 1
        for (int i = tid; i < 2 * BUF_SLOTS; i += NT) s4[i] = z;
    }
    __syncthreads();              // zeros visible before TA writes land

    STAGE(0, 0);                  // prologue stage into buffer 0

    const float* wbase = inp + (size_t)b * 81 * HW + (size_t)h * Wc + wc0;
    const float scale = 1.0f / (float)Cc;

    __syncthreads();              // drains vmcnt: stage(0) complete

    #pragma unroll 1
    for (int k = 0; k < NCHUNK; ++k) {
        const int bsel = k & 1;
        const float* bufS = sS + bsel * BUF_FLOATS;

        float4 wA[9], wB[9];
        LOADW(wA, 0);

        float acc[NC][NPIX];
        #pragma unroll
        for (int j = 0; j < NC; ++j)
            #pragma unroll
            for (int i = 0; i < NPIX; ++i) acc[j][i] = 0.f;

        // software-pipelined P loop; all weight loads/waits precede the stage
        LOADW(wB, 1); COMPUTE(wA, 0);
        LOADW(wA, 2); COMPUTE(wB, 1);
        LOADW(wB, 3); COMPUTE(wA, 2);
        LOADW(wA, 4); COMPUTE(wB, 3);
        LOADW(wB, 5); COMPUTE(wA, 4);
        LOADW(wA, 6); COMPUTE(wB, 5);
        LOADW(wB, 7); COMPUTE(wA, 6);
        LOADW(wA, 8); COMPUTE(wB, 7);

        // stage(k+1) is the YOUNGEST vmem: no weight wait can drain it; it
        // overlaps COMPUTE(P=8) + stores, then the barrier's vmcnt(0) drains it.
        __builtin_amdgcn_sched_barrier(0);
        if (k + 1 < NCHUNK) STAGE(k + 1, bsel ^ 1);
        __builtin_amdgcn_sched_barrier(0);

        COMPUTE(wA, 8);

        // ---- store this chunk's outputs (plain stores: L2 write-combines) ----
        #pragma unroll
        for (int j = 0; j < NC; ++j) {
            const int c = k * CHUNK + j * NSLOT + slot;
            float* op = out + (((size_t)(b * Cc + c)) * Hc + h) * Wc + wc0;
            float4 v = make_float4(acc[j][0] * scale, acc[j][1] * scale,
                                   acc[j][2] * scale, acc[j][3] * scale);
            *reinterpret_cast<float4*>(op) = v;
        }

        __syncthreads(); // all reads of bufS done + stage(k+1) landed
    }
}

extern "C" void kernel_launch(void* const* d_in, const int* in_sizes, int n_in,
                              void* d_out, int out_size, void* d_ws, size_t ws_size,
                              hipStream_t stream) {
    const float* inp    = (const float*)d_in[0]; // (8, 81, 128, 128)
    const float* second = (const float*)d_in[1]; // (8, 256, 128, 128)
    float* outp         = (float*)d_out;         // (8, 256, 128, 128)

    dim3 grid(Bc * (Hc / TH) * (Wc / TW)); // 512 blocks
    dim3 block(NT);
    fct_kernel<<<grid, block, 0, stream>>>(inp, second, outp);
}

// Round 6
// 577.665 us; speedup vs baseline: 4.2395x; 4.2395x over previous
//
#include <hip/hip_runtime.h>

// FunctionCorrelationTranspose:
// out[b,c,h,w] = (1/C) * sum_{P=0..8,O=0..8} input[b, P*9+O, h, w] * second[b, c, h+P-4, w+O-4]
// B=8, C=256, H=W=128, zero padding outside image.
//
// R4, attempt 3 (two broker-side container failures; kernel never executed):
// occupancy-first. R0's proven loop structure, but CHUNK 32->16 channels:
//   - LDS/block 74->37 KB  => 4 blocks/CU, 16 waves/CU (~45% occupancy, was 22.7%)
//   - NC 4->2 keeps VGPR under the 128 cap for 4 blocks/CU
//   - staging via global_load_lds width-16 (no staging VALU / ds_writes)
//   - plain float4 stores (R2's nontemporal stores caused RMW write amplification)
//   - NO full unroll / ping-pong (R3's full unroll spilled ~12KB/thread to scratch:
//     WRITE_SIZE 3.4 GB, VALUBusy 2.7%)

#define MD 4

constexpr int Bc = 8, Cc = 256, Hc = 128, Wc = 128;
constexpr int HW = Hc * Wc;
constexpr int TH = 16, TW = 16;          // spatial tile per block
constexpr int NSLOT = 8;                 // channel slots (threads along C)
constexpr int NC = 2;                    // channels per thread per chunk
constexpr int CHUNK = NSLOT * NC;        // 16 channels staged in LDS at a time
constexpr int NCHUNK = Cc / CHUNK;       // 16
constexpr int SROWS = TH + 2 * MD;       // 24
constexpr int SCOLS = TW + 2 * MD;       // 24
constexpr int CH_STRIDE = SROWS * SCOLS + 4; // 580 floats; slot bank-starts {0,4,..,28}
constexpr int SLOTS_PER_CH = CH_STRIDE / 4;  // 145 16B-slots per channel (144 data + 1 pad)
constexpr int TOT_SLOTS = CHUNK * SLOTS_PER_CH; // 2320
constexpr int NPIX = 8;                  // pixels per thread (contiguous in w)

__global__ __launch_bounds__(256, 4)
void fct_kernel(const float* __restrict__ inp,    // (B, 81, H, W)
                const float* __restrict__ second, // (B, C, H, W)
                float* __restrict__ out)          // (B, C, H, W)
{
    __shared__ __attribute__((aligned(16))) float sS[CHUNK * CH_STRIDE]; // 37,120 B

    const int tid   = threadIdx.x;
    const int slot  = tid & (NSLOT - 1);   // 0..7
    const int group = tid >> 3;            // 0..31
    const int r     = group >> 1;          // 0..15 tile row
    const int seg   = group & 1;           // 0..1  8-px segment in row
    const int wid   = tid >> 6;            // wave id 0..3

    const int bx   = blockIdx.x;           // 0..511
    const int b    = bx >> 6;
    const int tile = bx & 63;
    const int th0  = (tile >> 3) * TH;
    const int tw0  = (tile & 7) * TW;

    const int h   = th0 + r;
    const int wc0 = tw0 + seg * NPIX;

    // zero LDS once: OOB halo cells must read as 0.  Staging never writes OOB
    // slots (exec-masked) nor the per-channel pad slot, so zeros persist.
    {
        float4 z = make_float4(0.f, 0.f, 0.f, 0.f);
        float4* s4 = reinterpret_cast<float4*>(sS);
        #pragma unroll 1
        for (int i = tid; i < TOT_SLOTS; i += 256) s4[i] = z;
    }

    const float* wbase = inp + (size_t)b * 81 * HW + (size_t)h * Wc + wc0;
    const float scale = 1.0f / (float)Cc;

    #pragma unroll 1
    for (int chunk = 0; chunk < NCHUNK; ++chunk) {
        __syncthreads(); // previous chunk's compute done before overwrite (and after zeroing)

        // ---- stage second[b, chunk*16 .. +16) halo tile into LDS, async ----
        // LDS image is linear in 16B slots: slot m = ch*145 + k, k<144 data, k==144 pad.
        // global_load_lds writes wave-uniform base + lane*16, which matches m exactly.
        {
            const int c0 = chunk * CHUNK;
            #pragma unroll
            for (int it = 0; it < 10; ++it) {
                const int m = it * 256 + tid;
                if (m < TOT_SLOTS) {
                    const int ch   = m / SLOTS_PER_CH;      // /145 (magic mul)
                    const int k    = m - ch * SLOTS_PER_CH; // 0..144
                    const int row  = k / 6;
                    const int x    = k - row * 6;
                    const int grow = th0 - MD + row;
                    const int gcol = tw0 - MD + 4 * x;      // multiple of 4: fully in or out
                    float* ldsb = &sS[(size_t)(it * 256 + wid * 64) * 4]; // wave-uniform
                    if (k < 144 && grow >= 0 && grow < Hc && gcol >= 0 && gcol <= Wc - 4) {
                        const float* gp = second +
                            (((size_t)(b * Cc + c0 + ch)) * Hc + grow) * Wc + gcol;
                        __builtin_amdgcn_global_load_lds(
                            (const __attribute__((address_space(1))) void*)gp,
                            (__attribute__((address_space(3))) void*)ldsb,
                            16, 0, 0);
                    }
                }
            }
        }
        __syncthreads(); // drains vmcnt: staging complete

        float acc[NC][NPIX];
        #pragma unroll
        for (int j = 0; j < NC; ++j)
            #pragma unroll
            for (int i = 0; i < NPIX; ++i) acc[j][i] = 0.f;

        #pragma unroll 1
        for (int P = 0; P < 9; ++P) {
            // this tap-row's weights for our 8 pixels: 9 taps x 8 px
            float wv[9][8];
            #pragma unroll
            for (int o = 0; o < 9; ++o) {
                const float* wp = wbase + (size_t)(P * 9 + o) * HW;
                float4 a0 = *reinterpret_cast<const float4*>(wp);
                float4 a1 = *reinterpret_cast<const float4*>(wp + 4);
                wv[o][0] = a0.x; wv[o][1] = a0.y; wv[o][2] = a0.z; wv[o][3] = a0.w;
                wv[o][4] = a1.x; wv[o][5] = a1.y; wv[o][6] = a1.z; wv[o][7] = a1.w;
            }
            #pragma unroll
            for (int j = 0; j < NC; ++j) {
                const int cl = j * NSLOT + slot;
                const float* srow = &sS[cl * CH_STRIDE + (r + P) * SCOLS + seg * NPIX];
                float s[16];
                #pragma unroll
                for (int t = 0; t < 4; ++t) {
                    float4 v = *reinterpret_cast<const float4*>(srow + 4 * t);
                    s[4*t] = v.x; s[4*t+1] = v.y; s[4*t+2] = v.z; s[4*t+3] = v.w;
                }
                #pragma unroll
                for (int o = 0; o < 9; ++o)
                    #pragma unroll
                    for (int i = 0; i < NPIX; ++i)
                        acc[j][i] = fmaf(wv[o][i], s[i + o], acc[j][i]);
            }
        }

        // ---- store this chunk's outputs ----
        #pragma unroll
        for (int j = 0; j < NC; ++j) {
            const int c = chunk * CHUNK + j * NSLOT + slot;
            float* op = out + (((size_t)(b * Cc + c)) * Hc + h) * Wc + wc0;
            float4 v0 = make_float4(acc[j][0] * scale, acc[j][1] * scale,
                                    acc[j][2] * scale, acc[j][3] * scale);
            float4 v1 = make_float4(acc[j][4] * scale, acc[j][5] * scale,
                                    acc[j][6] * scale, acc[j][7] * scale);
            *reinterpret_cast<float4*>(op)     = v0;
            *reinterpret_cast<float4*>(op + 4) = v1;
        }
    }
}

extern "C" void kernel_launch(void* const* d_in, const int* in_sizes, int n_in,
                              void* d_out, int out_size, void* d_ws, size_t ws_size,
                              hipStream_t stream) {
    const float* inp    = (const float*)d_in[0]; // (8, 81, 128, 128)
    const float* second = (const float*)d_in[1]; // (8, 256, 128, 128)
    float* outp         = (float*)d_out;         // (8, 256, 128, 128)

    dim3 grid(Bc * (Hc / TH) * (Wc / TW)); // 512 blocks
    dim3 block(256);
    fct_kernel<<<grid, block, 0, stream>>>(inp, second, outp);
}